// Round 1
// baseline (188.179 us; speedup 1.0000x reference)
//
#include <hip/hip_runtime.h>

// DetectionLoss: YOLO-style 3-layer loss.
// Round 6: SINGLE-LAUNCH. k3 folded into K as a dedicated finalizer block
// using an init-free completion handshake: each producer block publishes
// partials with agent-scope relaxed atomic stores, then release-stores a
// flag PAIR (MAGIC, ~MAGIC). A constant-dword poison fill leaves (P,P),
// which can never satisfy lo==MAGIC && hi==~MAGIC, so no zero-init /
// memset / cooperative launch is needed. Finalizer (block 458) spins on
// the 458 pairs with agent-scope acquire loads (cross-XCD safe), then
// computes the final loss exactly as k3 did. All 459 blocks are
// co-resident (4 waves, ~12.6KB LDS each) -> no deadlock possible.
// Geometry: obj 394 blocks x 1024 cells (4 loads in flight/thread),
// cls 60 blocks x 4096 jobs, box 4 blocks (unchanged).
//
// ws float layout:
//   [bblk*16 + 0..8]    box-block partials (npos[3], bbox[3], corr[3]), bblk<4
//   [64 + i]            obj partials, i<394 (i<300 -> L0, <375 -> L1, else L2)
//   [512 + cblk*3+l]    cls partials, cblk<60
//   [1024 + 2i, +2i+1]  flag pairs (uint32), i<458

#define NCLS 80
#define NCH 85
#define OBJ_BLOCKS 394     // 300 + 75 + 19, 1024 cells each
#define CLS_BLOCKS 60      // 60*4096 == 3072*80 jobs exactly
#define BOX_BLOCKS 4
#define NPROD (OBJ_BLOCKS + CLS_BLOCKS + BOX_BLOCKS)   // 458
#define TOT_BLOCKS (NPROD + 1)
#define OBJ_PART_OFF 64
#define CLS_PART_OFF 512
#define FLAG_OFF 1024
#define MAGIC_LO 0x1B7F3C5Du
#define MAGIC_HI 0xE480C3A2u   // ~MAGIC_LO

__device__ __forceinline__ float bce0(float x) {
    return fmaxf(x, 0.0f) + log1pf(expf(-fabsf(x)));
}

__device__ __forceinline__ float ciou_loss(float px, float py, float pw, float ph,
                                           float tx, float ty, float tw, float th) {
    float p0 = px - pw * 0.5f, p1 = py - ph * 0.5f, p2 = px + pw * 0.5f, p3 = py + ph * 0.5f;
    float t0 = tx - tw * 0.5f, t1 = ty - th * 0.5f, t2 = tx + tw * 0.5f, t3 = ty + th * 0.5f;
    float ix1 = fmaxf(p0, t0), iy1 = fmaxf(p1, t1);
    float ix2 = fminf(p2, t2), iy2 = fminf(p3, t3);
    float inter = fmaxf(ix2 - ix1, 0.0f) * fmaxf(iy2 - iy1, 0.0f);
    float a1 = (p2 - p0) * (p3 - p1);
    float a2 = (t2 - t0) * (t3 - t1);
    float iou = inter / (a1 + a2 - inter + 1e-7f);
    float pcx = (p0 + p2) * 0.5f, pcy = (p1 + p3) * 0.5f;
    float tcx = (t0 + t2) * 0.5f, tcy = (t1 + t3) * 0.5f;
    float cd = (pcx - tcx) * (pcx - tcx) + (pcy - tcy) * (pcy - tcy);
    float ex1 = fminf(p0, t0), ey1 = fminf(p1, t1);
    float ex2 = fmaxf(p2, t2), ey2 = fmaxf(p3, t3);
    float dd = (ex2 - ex1) * (ex2 - ex1) + (ey2 - ey1) * (ey2 - ey1);
    return 1.0f - (iou - cd / (dd + 1e-7f));
}

// detect 'valid' storage layout (uint8 / int32 / float32) from byte patterns.
__device__ __forceinline__ int detect_valid_flag(const unsigned char* validb, int t,
                                                 int* s_nz, int* s_flag) {
    if (t < 4) s_nz[t] = 0;
    __syncthreads();
    {
        int nz = 0;
#pragma unroll
        for (int j = 0; j < 4; j++) if (validb[t * 4 + j]) nz |= (1 << j);
        if (nz & 1) atomicOr(&s_nz[0], 1);
        if (nz & 2) atomicOr(&s_nz[1], 1);
        if (nz & 4) atomicOr(&s_nz[2], 1);
        if (nz & 8) atomicOr(&s_nz[3], 1);
    }
    __syncthreads();
    if (t == 0) {
        int f;
        if (!s_nz[1] && !s_nz[2] && !s_nz[3]) f = 0;      // int32
        else if (!s_nz[0] && !s_nz[1]) f = 2;             // float32
        else f = 1;                                        // uint8
        *s_flag = f;
    }
    __syncthreads();
    return *s_flag;
}

__device__ __forceinline__ bool read_valid(const unsigned char* validb, int bm, int flag) {
    if (flag == 0) return ((const int*)validb)[bm] != 0;
    if (flag == 1) return validb[bm] != 0;
    return ((const float*)validb)[bm] != 0.0f;
}

__device__ __forceinline__ void match_box(
    const float* __restrict__ boxes, const float* __restrict__ anchors,
    bool valid, int bm, int l, int gdim,
    bool& pos, int& ba, int& gx, int& gy,
    float& cx, float& cy, float& w, float& h)
{
    const float x1 = boxes[bm * 4 + 0], y1 = boxes[bm * 4 + 1];
    const float x2 = boxes[bm * 4 + 2], y2 = boxes[bm * 4 + 3];
    const float g = (float)gdim;
    cx = (x1 + x2) * 0.5f * g;
    cy = (y1 + y2) * 0.5f * g;
    w = (x2 - x1) * g;
    h = (y2 - y1) * g;
    float best = -1.0f; ba = 0;
#pragma unroll
    for (int a = 0; a < 3; a++) {
        const float aw = anchors[l * 6 + a * 2 + 0];
        const float ah = anchors[l * 6 + a * 2 + 1];
        const float inter = fminf(w, aw) * fminf(h, ah);
        const float uni = w * h + aw * ah - inter;
        const float iou = inter / (uni + 1e-6f);
        if (iou > best) { best = iou; ba = a; }   // jnp.argmax first-max tie-break
    }
    pos = valid && (best > 0.5f);
    gx = (int)cx; gx = gx < 0 ? 0 : (gx > gdim - 1 ? gdim - 1 : gx);
    gy = (int)cy; gy = gy < 0 ? 0 : (gy > gdim - 1 ? gdim - 1 : gy);
}

// publish one partial with agent scope (bypasses non-coherent per-XCD caches)
__device__ __forceinline__ void pub1(float* ws, int idx, float v) {
    __hip_atomic_store(&ws[idx], v, __ATOMIC_RELAXED, __HIP_MEMORY_SCOPE_AGENT);
}

// flag pair: HI relaxed first, LO release last. Reader requires BOTH to match;
// LO's release synchronizes-with the reader's acquire -> partials visible.
__device__ __forceinline__ void signal_done(float* ws, int blk) {
    unsigned int* u = (unsigned int*)ws;
    __hip_atomic_store(&u[FLAG_OFF + 2 * blk + 1], MAGIC_HI, __ATOMIC_RELAXED, __HIP_MEMORY_SCOPE_AGENT);
    __hip_atomic_store(&u[FLAG_OFF + 2 * blk + 0], MAGIC_LO, __ATOMIC_RELEASE, __HIP_MEMORY_SCOPE_AGENT);
}

__global__ __launch_bounds__(256) void K(
    const float* __restrict__ p3, const float* __restrict__ p4, const float* __restrict__ p5,
    const float* __restrict__ boxes, const int* __restrict__ labels,
    const unsigned char* __restrict__ validb, const float* __restrict__ anchors,
    float* __restrict__ ws, float* __restrict__ out)
{
    const int blk = blockIdx.x, t = threadIdx.x;
    const int GDIM[3] = {80, 40, 20};

    if (blk < OBJ_BLOCKS) {
        // ---- obj: sum BCE(x,0) over obj channel, 1024 cells per block ----
        int cell0, ncell;
        const float* base;
        if (blk < 300)      { cell0 = blk * 1024;         ncell = 307200; base = p3; }
        else if (blk < 375) { cell0 = (blk - 300) * 1024; ncell = 76800;  base = p4; }
        else                { cell0 = (blk - 375) * 1024; ncell = 19200;  base = p5; }
        float acc = 0.0f;
#pragma unroll
        for (int k = 0; k < 4; k++) {
            const int cell = cell0 + k * 256 + t;
            if (cell < ncell) acc += bce0(base[(size_t)cell * NCH + 4]);
        }
#pragma unroll
        for (int off = 32; off > 0; off >>= 1) acc += __shfl_down(acc, off);
        __shared__ float s[4];
        if ((t & 63) == 0) s[t >> 6] = acc;
        __syncthreads();
        if (t == 0) {
            pub1(ws, OBJ_PART_OFF + blk, s[0] + s[1] + s[2] + s[3]);
            signal_done(ws, blk);
        }
    } else if (blk < OBJ_BLOCKS + CLS_BLOCKS) {
        // ---- cls: static job mapping, recompute positivity per job ----
        __shared__ int s_nz[4], s_flag;
        const int flag = detect_valid_flag(validb, t, s_nz, &s_flag);
        const int cblk = blk - OBJ_BLOCKS;
        float a0 = 0.0f, a1 = 0.0f, a2 = 0.0f;
#pragma unroll 4
        for (int k = 0; k < 16; k++) {
            const int job = cblk * 4096 + k * 256 + t;   // < 245760 always
            const int rec = job / NCLS;
            const int c = job - rec * NCLS;
            const int bm = rec / 3;
            const int l = rec - bm * 3;
            const bool valid = read_valid(validb, bm, flag);
            bool pos; int ba, gx, gy; float cx, cy, w, h;
            match_box(boxes, anchors, valid, bm, l, GDIM[l], pos, ba, gx, gy, cx, cy, w, h);
            if (pos) {
                const int b = bm >> 6;
                const int g = GDIM[l];
                const int idx = (((b * 3 + ba) * g + gy) * g + gx) * NCH;
                const float* base = (l == 0) ? p3 : ((l == 1) ? p4 : p5);
                const float logit = base[idx + 5 + c];
                const float tv = (c == labels[bm]) ? 1.0f : 0.0f;
                const float bce = fmaxf(logit, 0.0f) - logit * tv + log1pf(expf(-fabsf(logit)));
                a0 += (l == 0) ? bce : 0.0f;
                a1 += (l == 1) ? bce : 0.0f;
                a2 += (l == 2) ? bce : 0.0f;
            }
        }
#pragma unroll
        for (int off = 32; off > 0; off >>= 1) {
            a0 += __shfl_down(a0, off);
            a1 += __shfl_down(a1, off);
            a2 += __shfl_down(a2, off);
        }
        __shared__ float s3[4][3];
        if ((t & 63) == 0) { s3[t >> 6][0] = a0; s3[t >> 6][1] = a1; s3[t >> 6][2] = a2; }
        __syncthreads();
        if (t == 0) {
            pub1(ws, CLS_PART_OFF + cblk * 3 + 0, s3[0][0] + s3[1][0] + s3[2][0] + s3[3][0]);
            pub1(ws, CLS_PART_OFF + cblk * 3 + 1, s3[0][1] + s3[1][1] + s3[2][1] + s3[3][1]);
            pub1(ws, CLS_PART_OFF + cblk * 3 + 2, s3[0][2] + s3[1][2] + s3[2][2] + s3[3][2]);
            signal_done(ws, blk);
        }
    } else if (blk < NPROD) {
        // ---- box: npos / CIoU / obj-corr with dedupe, 256 boxes per block ----
        __shared__ int s_nz[4], s_flag;
        __shared__ int s_info[3][1024];   // packed: pos<<16 | a<<14 | gy<<7 | gx
        __shared__ float s_bacc[9];       // npos[3], bbox[3], corr[3]
        const int flag = detect_valid_flag(validb, t, s_nz, &s_flag);
        if (t < 9) s_bacc[t] = 0.0f;
        // phase 1: full info table (all 1024 boxes x 3 layers) for global dedupe
#pragma unroll
        for (int j = 0; j < 4; j++) {
            const int bm = t + j * 256;
            const bool valid = read_valid(validb, bm, flag);
#pragma unroll
            for (int l = 0; l < 3; l++) {
                bool pos; int ba, gx, gy; float cx, cy, w, h;
                match_box(boxes, anchors, valid, bm, l, GDIM[l], pos, ba, gx, gy, cx, cy, w, h);
                s_info[l][bm] = (pos ? (1 << 16) : 0) | (ba << 14) | (gy << 7) | gx;
            }
        }
        __syncthreads();
        // phase 2: this block's 256-box slice
        const int bblk = blk - OBJ_BLOCKS - CLS_BLOCKS;
        const int bm = bblk * 256 + t;
        const int b = bm >> 6;
        const int m = bm & 63;
        const bool valid = read_valid(validb, bm, flag);
#pragma unroll
        for (int l = 0; l < 3; l++) {
            const int info = s_info[l][bm];
            if (info & (1 << 16)) {
                const int ba = (info >> 14) & 3, gy = (info >> 7) & 127, gx = info & 127;
                const int g = GDIM[l];
                const int idx = (((b * 3 + ba) * g + gy) * g + gx) * NCH;
                const float* base = (l == 0) ? p3 : ((l == 1) ? p4 : p5);
                bool pos; int ba2, gx2, gy2; float cx, cy, w, h;
                match_box(boxes, anchors, valid, bm, l, GDIM[l], pos, ba2, gx2, gy2, cx, cy, w, h);
                atomicAdd(&s_bacc[0 + l], 1.0f);
                const float bb = ciou_loss(base[idx + 0], base[idx + 1], base[idx + 2], base[idx + 3],
                                           cx, cy, w, h);
                atomicAdd(&s_bacc[3 + l], bb);
                // dedupe: lowest-m box (global order) owning this cell adds the correction
                bool dup = false;
                const int rowbase = b * 64;
                for (int mm = rowbase; mm < rowbase + m; mm++) {
                    if (s_info[l][mm] == info) { dup = true; break; }
                }
                if (!dup) atomicAdd(&s_bacc[6 + l], base[idx + 4]);
            }
        }
        __syncthreads();
        if (t == 0) {
#pragma unroll
            for (int r = 0; r < 9; r++) pub1(ws, bblk * 16 + r, s_bacc[r]);
            signal_done(ws, blk);
        }
    } else {
        // ---- finalizer: spin on 458 flag pairs, then reduce + final formula ----
        unsigned int* u = (unsigned int*)ws;
        int first = 1;
        for (;;) {
            int ok = 1;
            for (int i = t; i < NPROD; i += 256) {
                const unsigned int lo = __hip_atomic_load(&u[FLAG_OFF + 2 * i + 0],
                                                          __ATOMIC_ACQUIRE, __HIP_MEMORY_SCOPE_AGENT);
                const unsigned int hi = __hip_atomic_load(&u[FLAG_OFF + 2 * i + 1],
                                                          __ATOMIC_ACQUIRE, __HIP_MEMORY_SCOPE_AGENT);
                ok &= (lo == MAGIC_LO) & (hi == MAGIC_HI);
            }
            if (__syncthreads_and(ok)) break;
            if (!first) __builtin_amdgcn_s_sleep(8);
            first = 0;
        }
        __shared__ float s_acc[16];  // [0..2]npos [3..5]bbox [6..8]corr [9..11]obj [12..14]cls
        if (t < 16) s_acc[t] = 0.0f;
        __syncthreads();
        for (int i = t; i < OBJ_BLOCKS; i += 256) {
            const int l = (i < 300) ? 0 : ((i < 375) ? 1 : 2);
            const float v = __hip_atomic_load(&ws[OBJ_PART_OFF + i],
                                              __ATOMIC_RELAXED, __HIP_MEMORY_SCOPE_AGENT);
            atomicAdd(&s_acc[9 + l], v);
        }
        for (int i = t; i < CLS_BLOCKS * 3; i += 256) {
            const float v = __hip_atomic_load(&ws[CLS_PART_OFF + i],
                                              __ATOMIC_RELAXED, __HIP_MEMORY_SCOPE_AGENT);
            atomicAdd(&s_acc[12 + i % 3], v);
        }
        if (t < BOX_BLOCKS * 9) {
            const int bblk = t / 9, r = t % 9;
            const float v = __hip_atomic_load(&ws[bblk * 16 + r],
                                              __ATOMIC_RELAXED, __HIP_MEMORY_SCOPE_AGENT);
            atomicAdd(&s_acc[r], v);
        }
        __syncthreads();
        if (t == 0) {
            float cls = 0.0f, obj = 0.0f, box = 0.0f;
            const float GRID[3] = {307200.0f, 76800.0f, 19200.0f};
            for (int l = 0; l < 3; l++) {
                const float npos = s_acc[l];
                const float has = npos > 0.0f ? 1.0f : 0.0f;
                const float denom = fmaxf(npos, 1.0f);
                cls += has * s_acc[12 + l] / (denom * 80.0f);
                box += has * s_acc[3 + l] / denom;
                obj += has * (s_acc[9 + l] - s_acc[6 + l]) / GRID[l];
            }
            out[0] = 0.5f * cls + 1.0f * obj + 0.05f * box;
        }
    }
}

extern "C" void kernel_launch(void* const* d_in, const int* in_sizes, int n_in,
                              void* d_out, int out_size, void* d_ws, size_t ws_size,
                              hipStream_t stream) {
    const float* p3 = (const float*)d_in[0];
    const float* p4 = (const float*)d_in[1];
    const float* p5 = (const float*)d_in[2];
    const float* boxes = (const float*)d_in[3];
    const int* labels = (const int*)d_in[4];
    const unsigned char* validb = (const unsigned char*)d_in[5];
    const float* anchors = (const float*)d_in[6];
    float* ws = (float*)d_ws;
    float* out = (float*)d_out;

    K<<<TOT_BLOCKS, 256, 0, stream>>>(p3, p4, p5, boxes, labels, validb, anchors, ws, out);
}

// Round 2
// 182.358 us; speedup vs baseline: 1.0319x; 1.0319x over previous
//
#include <hip/hip_runtime.h>
#include <hip/hip_bf16.h>

// DetectionLoss: YOLO-style 3-layer loss.
// Round 7: REVERT to the Round-5 two-launch structure (harness-verified
// 183.7/183.4us). Round 6's single-launch agent-scope handshake regressed
// (+4.8us): the finalizer's acquire-poll loop forces per-poll L2
// invalidations on its XCD (starving ~57 co-resident producer blocks) and
// each of 458 producer release-stores pays a cross-XCD writeback -- more
// than the one dispatch + gap (~3-4us) the merge saved. The kernel-boundary
// sync of the two-launch version is cheaper than emulating it with
// agent-scope atomics.
//
// Structure: k1 merged into the big kernel. cls jobs use a STATIC mapping
// (3072 potential records x 80 classes = 245,760 jobs = 240x1024) and
// recompute positivity (~30 VALU) per job. Per-box work (npos/CIoU/
// obj-corr+dedupe) rides along as 4 blocks that rebuild the full info
// table in LDS. Every block writes its own private partial slot
// unconditionally -> NO global atomics, NO zero-init, poison-safe.
//
// ws float layout:
//   [bblk*16 + 0..8]   box-block partials (npos[3], bbox[3], corr[3]), bblk<4
//   [64 + i]           obj partials, i<788 (i<600 -> L0, <750 -> L1, else L2)
//   [1024 + cblk*3+l]  cls partials, cblk<240

#define NCLS 80
#define NCH 85
#define OBJ_BLOCKS 788     // 600 + 150 + 38, 512 cells each
#define CLS_BLOCKS 240     // 240*1024 == 3072*80 jobs exactly
#define BOX_BLOCKS 4
#define TOT_BLOCKS (OBJ_BLOCKS + CLS_BLOCKS + BOX_BLOCKS)
#define OBJ_PART_OFF 64
#define CLS_PART_OFF 1024

__device__ __forceinline__ float bce0(float x) {
    return fmaxf(x, 0.0f) + log1pf(expf(-fabsf(x)));
}

__device__ __forceinline__ float ciou_loss(float px, float py, float pw, float ph,
                                           float tx, float ty, float tw, float th) {
    float p0 = px - pw * 0.5f, p1 = py - ph * 0.5f, p2 = px + pw * 0.5f, p3 = py + ph * 0.5f;
    float t0 = tx - tw * 0.5f, t1 = ty - th * 0.5f, t2 = tx + tw * 0.5f, t3 = ty + th * 0.5f;
    float ix1 = fmaxf(p0, t0), iy1 = fmaxf(p1, t1);
    float ix2 = fminf(p2, t2), iy2 = fminf(p3, t3);
    float inter = fmaxf(ix2 - ix1, 0.0f) * fmaxf(iy2 - iy1, 0.0f);
    float a1 = (p2 - p0) * (p3 - p1);
    float a2 = (t2 - t0) * (t3 - t1);
    float iou = inter / (a1 + a2 - inter + 1e-7f);
    float pcx = (p0 + p2) * 0.5f, pcy = (p1 + p3) * 0.5f;
    float tcx = (t0 + t2) * 0.5f, tcy = (t1 + t3) * 0.5f;
    float cd = (pcx - tcx) * (pcx - tcx) + (pcy - tcy) * (pcy - tcy);
    float ex1 = fminf(p0, t0), ey1 = fminf(p1, t1);
    float ex2 = fmaxf(p2, t2), ey2 = fmaxf(p3, t3);
    float dd = (ex2 - ex1) * (ex2 - ex1) + (ey2 - ey1) * (ey2 - ey1);
    return 1.0f - (iou - cd / (dd + 1e-7f));
}

// detect 'valid' storage layout (uint8 / int32 / float32) from byte patterns.
// 256 threads scan the 1024-byte window; returns 0=int32, 1=uint8, 2=float32.
__device__ __forceinline__ int detect_valid_flag(const unsigned char* validb, int t,
                                                 int* s_nz, int* s_flag) {
    if (t < 4) s_nz[t] = 0;
    __syncthreads();
    {
        int nz = 0;
#pragma unroll
        for (int j = 0; j < 4; j++) if (validb[t * 4 + j]) nz |= (1 << j);
        if (nz & 1) atomicOr(&s_nz[0], 1);
        if (nz & 2) atomicOr(&s_nz[1], 1);
        if (nz & 4) atomicOr(&s_nz[2], 1);
        if (nz & 8) atomicOr(&s_nz[3], 1);
    }
    __syncthreads();
    if (t == 0) {
        int f;
        if (!s_nz[1] && !s_nz[2] && !s_nz[3]) f = 0;      // int32
        else if (!s_nz[0] && !s_nz[1]) f = 2;             // float32
        else f = 1;                                        // uint8
        *s_flag = f;
    }
    __syncthreads();
    return *s_flag;
}

__device__ __forceinline__ bool read_valid(const unsigned char* validb, int bm, int flag) {
    if (flag == 0) return ((const int*)validb)[bm] != 0;
    if (flag == 1) return validb[bm] != 0;
    return ((const float*)validb)[bm] != 0.0f;
}

// anchor match for box bm at layer l: returns pos, best anchor, cell, cx/cy/w/h
__device__ __forceinline__ void match_box(
    const float* __restrict__ boxes, const float* __restrict__ anchors,
    bool valid, int bm, int l, int gdim,
    bool& pos, int& ba, int& gx, int& gy,
    float& cx, float& cy, float& w, float& h)
{
    const float x1 = boxes[bm * 4 + 0], y1 = boxes[bm * 4 + 1];
    const float x2 = boxes[bm * 4 + 2], y2 = boxes[bm * 4 + 3];
    const float g = (float)gdim;
    cx = (x1 + x2) * 0.5f * g;
    cy = (y1 + y2) * 0.5f * g;
    w = (x2 - x1) * g;
    h = (y2 - y1) * g;
    float best = -1.0f; ba = 0;
#pragma unroll
    for (int a = 0; a < 3; a++) {
        const float aw = anchors[l * 6 + a * 2 + 0];
        const float ah = anchors[l * 6 + a * 2 + 1];
        const float inter = fminf(w, aw) * fminf(h, ah);
        const float uni = w * h + aw * ah - inter;
        const float iou = inter / (uni + 1e-6f);
        if (iou > best) { best = iou; ba = a; }   // jnp.argmax first-max tie-break
    }
    pos = valid && (best > 0.5f);
    gx = (int)cx; gx = gx < 0 ? 0 : (gx > gdim - 1 ? gdim - 1 : gx);
    gy = (int)cy; gy = gy < 0 ? 0 : (gy > gdim - 1 ? gdim - 1 : gy);
}

__global__ __launch_bounds__(256) void K(
    const float* __restrict__ p3, const float* __restrict__ p4, const float* __restrict__ p5,
    const float* __restrict__ boxes, const int* __restrict__ labels,
    const unsigned char* __restrict__ validb, const float* __restrict__ anchors,
    float* __restrict__ ws)
{
    const int blk = blockIdx.x, t = threadIdx.x;
    const int GDIM[3] = {80, 40, 20};

    if (blk < OBJ_BLOCKS) {
        // ---- obj: sum BCE(x,0) over obj channel, 512 cells per block ----
        int layer, cell0, ncell;
        const float* base;
        if (blk < 600)      { layer = 0; cell0 = blk * 512;         ncell = 307200; base = p3; }
        else if (blk < 750) { layer = 1; cell0 = (blk - 600) * 512; ncell = 76800;  base = p4; }
        else                { layer = 2; cell0 = (blk - 750) * 512; ncell = 19200;  base = p5; }
        float acc = 0.0f;
#pragma unroll
        for (int k = 0; k < 2; k++) {
            const int cell = cell0 + k * 256 + t;
            if (cell < ncell) acc += bce0(base[(size_t)cell * NCH + 4]);
        }
#pragma unroll
        for (int off = 32; off > 0; off >>= 1) acc += __shfl_down(acc, off);
        __shared__ float s[4];
        if ((t & 63) == 0) s[t >> 6] = acc;
        __syncthreads();
        if (t == 0) ws[OBJ_PART_OFF + blk] = s[0] + s[1] + s[2] + s[3];
    } else if (blk < OBJ_BLOCKS + CLS_BLOCKS) {
        // ---- cls: static job mapping, recompute positivity per job ----
        __shared__ int s_nz[4], s_flag;
        const int flag = detect_valid_flag(validb, t, s_nz, &s_flag);
        const int cblk = blk - OBJ_BLOCKS;
        float a0 = 0.0f, a1 = 0.0f, a2 = 0.0f;
#pragma unroll
        for (int k = 0; k < 4; k++) {
            const int job = cblk * 1024 + k * 256 + t;   // < 245760 always
            const int rec = job / NCLS;
            const int c = job - rec * NCLS;
            const int bm = rec / 3;
            const int l = rec - bm * 3;
            const bool valid = read_valid(validb, bm, flag);
            bool pos; int ba, gx, gy; float cx, cy, w, h;
            match_box(boxes, anchors, valid, bm, l, GDIM[l], pos, ba, gx, gy, cx, cy, w, h);
            if (pos) {
                const int b = bm >> 6;
                const int g = GDIM[l];
                const int idx = (((b * 3 + ba) * g + gy) * g + gx) * NCH;
                const float* base = (l == 0) ? p3 : ((l == 1) ? p4 : p5);
                const float logit = base[idx + 5 + c];
                const float tv = (c == labels[bm]) ? 1.0f : 0.0f;
                const float bce = fmaxf(logit, 0.0f) - logit * tv + log1pf(expf(-fabsf(logit)));
                a0 += (l == 0) ? bce : 0.0f;
                a1 += (l == 1) ? bce : 0.0f;
                a2 += (l == 2) ? bce : 0.0f;
            }
        }
#pragma unroll
        for (int off = 32; off > 0; off >>= 1) {
            a0 += __shfl_down(a0, off);
            a1 += __shfl_down(a1, off);
            a2 += __shfl_down(a2, off);
        }
        __shared__ float s3[4][3];
        if ((t & 63) == 0) { s3[t >> 6][0] = a0; s3[t >> 6][1] = a1; s3[t >> 6][2] = a2; }
        __syncthreads();
        if (t == 0) {
            ws[CLS_PART_OFF + cblk * 3 + 0] = s3[0][0] + s3[1][0] + s3[2][0] + s3[3][0];
            ws[CLS_PART_OFF + cblk * 3 + 1] = s3[0][1] + s3[1][1] + s3[2][1] + s3[3][1];
            ws[CLS_PART_OFF + cblk * 3 + 2] = s3[0][2] + s3[1][2] + s3[2][2] + s3[3][2];
        }
    } else {
        // ---- box: npos / CIoU / obj-corr with dedupe, 256 boxes per block ----
        __shared__ int s_nz[4], s_flag;
        __shared__ int s_info[3][1024];   // packed: pos<<16 | a<<14 | gy<<7 | gx
        __shared__ float s_bacc[9];       // npos[3], bbox[3], corr[3]
        const int flag = detect_valid_flag(validb, t, s_nz, &s_flag);
        if (t < 9) s_bacc[t] = 0.0f;
        // phase 1: full info table (all 1024 boxes x 3 layers) for global dedupe
#pragma unroll
        for (int j = 0; j < 4; j++) {
            const int bm = t + j * 256;
            const bool valid = read_valid(validb, bm, flag);
#pragma unroll
            for (int l = 0; l < 3; l++) {
                bool pos; int ba, gx, gy; float cx, cy, w, h;
                match_box(boxes, anchors, valid, bm, l, GDIM[l], pos, ba, gx, gy, cx, cy, w, h);
                s_info[l][bm] = (pos ? (1 << 16) : 0) | (ba << 14) | (gy << 7) | gx;
            }
        }
        __syncthreads();
        // phase 2: this block's 256-box slice
        const int bblk = blk - OBJ_BLOCKS - CLS_BLOCKS;
        const int bm = bblk * 256 + t;
        const int b = bm >> 6;
        const int m = bm & 63;
        const bool valid = read_valid(validb, bm, flag);
#pragma unroll
        for (int l = 0; l < 3; l++) {
            const int info = s_info[l][bm];
            if (info & (1 << 16)) {
                const int ba = (info >> 14) & 3, gy = (info >> 7) & 127, gx = info & 127;
                const int g = GDIM[l];
                const int idx = (((b * 3 + ba) * g + gy) * g + gx) * NCH;
                const float* base = (l == 0) ? p3 : ((l == 1) ? p4 : p5);
                bool pos; int ba2, gx2, gy2; float cx, cy, w, h;
                match_box(boxes, anchors, valid, bm, l, GDIM[l], pos, ba2, gx2, gy2, cx, cy, w, h);
                atomicAdd(&s_bacc[0 + l], 1.0f);
                const float bb = ciou_loss(base[idx + 0], base[idx + 1], base[idx + 2], base[idx + 3],
                                           cx, cy, w, h);
                atomicAdd(&s_bacc[3 + l], bb);
                // dedupe: lowest-m box (global order) owning this cell adds the correction
                bool dup = false;
                const int rowbase = b * 64;
                for (int mm = rowbase; mm < rowbase + m; mm++) {
                    if (s_info[l][mm] == info) { dup = true; break; }
                }
                if (!dup) atomicAdd(&s_bacc[6 + l], base[idx + 4]);
            }
        }
        __syncthreads();
        if (t < 9) ws[bblk * 16 + t] = s_bacc[t];
    }
}

// k3: 256-thread finalize. Sums private partial slots; no atomics anywhere else.
__global__ __launch_bounds__(256) void k3(const float* __restrict__ ws, float* __restrict__ out) {
    __shared__ float s_acc[16];  // [0..2]npos [3..5]bbox [6..8]corr [9..11]obj [12..14]cls
    const int t = threadIdx.x;
    if (t < 16) s_acc[t] = 0.0f;
    __syncthreads();
    for (int i = t; i < OBJ_BLOCKS; i += 256) {
        const int l = (i < 600) ? 0 : ((i < 750) ? 1 : 2);
        atomicAdd(&s_acc[9 + l], ws[OBJ_PART_OFF + i]);
    }
    for (int i = t; i < CLS_BLOCKS * 3; i += 256) {
        atomicAdd(&s_acc[12 + i % 3], ws[CLS_PART_OFF + i]);
    }
    if (t < BOX_BLOCKS * 9) {
        const int bblk = t / 9, r = t % 9;
        atomicAdd(&s_acc[r], ws[bblk * 16 + r]);
    }
    __syncthreads();
    if (t == 0) {
        float cls = 0.0f, obj = 0.0f, box = 0.0f;
        const float GRID[3] = {307200.0f, 76800.0f, 19200.0f};
        for (int l = 0; l < 3; l++) {
            const float npos = s_acc[l];
            const float has = npos > 0.0f ? 1.0f : 0.0f;
            const float denom = fmaxf(npos, 1.0f);
            cls += has * s_acc[12 + l] / (denom * 80.0f);
            box += has * s_acc[3 + l] / denom;
            obj += has * (s_acc[9 + l] - s_acc[6 + l]) / GRID[l];
        }
        out[0] = 0.5f * cls + 1.0f * obj + 0.05f * box;
    }
}

extern "C" void kernel_launch(void* const* d_in, const int* in_sizes, int n_in,
                              void* d_out, int out_size, void* d_ws, size_t ws_size,
                              hipStream_t stream) {
    const float* p3 = (const float*)d_in[0];
    const float* p4 = (const float*)d_in[1];
    const float* p5 = (const float*)d_in[2];
    const float* boxes = (const float*)d_in[3];
    const int* labels = (const int*)d_in[4];
    const unsigned char* validb = (const unsigned char*)d_in[5];
    const float* anchors = (const float*)d_in[6];
    float* ws = (float*)d_ws;
    float* out = (float*)d_out;

    K<<<TOT_BLOCKS, 256, 0, stream>>>(p3, p4, p5, boxes, labels, validb, anchors, ws);
    k3<<<1, 256, 0, stream>>>(ws, out);
}